// Round 1
// baseline (221.802 us; speedup 1.0000x reference)
//
#include <hip/hip_runtime.h>

#define B_DIM   4096
#define IN_DIM  512
#define OUT_DIM 512
#define KTOT    (IN_DIM * 36)      // 18432
#define BM      128
#define BN      128
#define BK      64
#define KSPLIT  4
#define KPER    (KTOT / KSPLIT)    // 4608 = 128 whole i-blocks
#define STEPS   (KPER / BK)        // 72

using f32x4 = __attribute__((ext_vector_type(4))) float;
using s16x8 = __attribute__((ext_vector_type(8))) short;
using u32x4 = __attribute__((ext_vector_type(4))) unsigned int;

// f32 -> bf16 RNE (bit pattern in low 16)
__device__ __forceinline__ unsigned int f2bf(float f) {
    unsigned int u = __float_as_uint(f);
    return (u + 0x7FFFu + ((u >> 16) & 1u)) >> 16;
}

// Exact replication of np.linspace(-1,1,10) + searchsorted(knots[1:], xc, 'left') + clip.
// knots[k] = -1.0 + k*(2.0/9.0) in f64 matches numpy's arange*delta+start exactly.
__device__ __forceinline__ void spline_rec(float xv, unsigned int& w0, unsigned int& w1, int& seg) {
    float xc = fminf(fmaxf(xv, -1.0f), 1.0f);
    double xd = (double)xc;
    int s = 0;
#pragma unroll
    for (int k = 1; k <= 8; ++k)
        s += ((-1.0 + (double)k * (2.0 / 9.0)) < xd) ? 1 : 0;
    double lo = -1.0 + (double)s * (2.0 / 9.0);
    double hi = -1.0 + (double)(s + 1) * (2.0 / 9.0);
    float t  = (float)((xd - lo) / (hi - lo));
    float t2 = t * t, t3 = t2 * t;
    w0 = f2bf(1.0f) | (f2bf(t) << 16);   // k=base   : {1, t}
    w1 = f2bf(t2)   | (f2bf(t3) << 16);  // k=base+2 : {t^2, t^3}
    seg = s;
}

// Prepass 1: per (b,i) tpow record (8B) + seg (1B)
__global__ void prep_x_kernel(const float* __restrict__ x,
                              uint2* __restrict__ tp,
                              unsigned char* __restrict__ sg) {
    int idx = blockIdx.x * 256 + threadIdx.x;
    if (idx >= B_DIM * IN_DIM) return;
    unsigned int w0, w1; int s;
    spline_rec(x[idx], w0, w1, s);
    uint2 r; r.x = w0; r.y = w1;
    tp[idx] = r;
    sg[idx] = (unsigned char)s;
}

// Prepass 2: coeff f32 -> bf16, scale[j] folded in. Layout [OUT][KTOT] bf16.
__global__ void prep_coeff_kernel(const float* __restrict__ c,
                                  const float* __restrict__ scale,
                                  u32x4* __restrict__ cbf) {
    int idx = blockIdx.x * 256 + threadIdx.x;           // one per 8 f32
    if (idx >= (OUT_DIM * KTOT) / 8) return;
    long base = (long)idx * 8;
    int  j = (int)(base / KTOT);                        // 18432 % 8 == 0: no row straddle
    float s = scale[j];
    f32x4 a = *(const f32x4*)(c + base);
    f32x4 b = *(const f32x4*)(c + base + 4);
    u32x4 o;
    o.x = f2bf(a.x * s) | (f2bf(a.y * s) << 16);
    o.y = f2bf(a.z * s) | (f2bf(a.w * s) << 16);
    o.z = f2bf(b.x * s) | (f2bf(b.y * s) << 16);
    o.w = f2bf(b.z * s) | (f2bf(b.w * s) << 16);
    cbf[idx] = o;
}

// GEMM: y[b,j] += sum_k A[b,k]*Cbf[j,k], A constructed on the fly in LDS.
// Grid 512 = 32 mt x 4 nt x 4 ksplit. 256 threads = 4 waves, each wave 64x64.
template<bool PRE>
__launch_bounds__(256, 2)
__global__ void kan_gemm(const float* __restrict__ x,
                         const float* __restrict__ coeff,
                         const float* __restrict__ scale,
                         const unsigned short* __restrict__ cbf,
                         const uint2* __restrict__ tp,
                         const unsigned char* __restrict__ sg,
                         float* __restrict__ out) {
    // A: [128 rows][72 hw] -> 144B row stride (2-way bank aliasing = free)
    __shared__ unsigned short AsF[BM * 72];
    // B: fragment-order subtiles: chunk c (k-octet) * 128 j * 8 hw; offset = c*2048 + j*16 bytes
    __shared__ unsigned short BsF[8 * BN * 8];

    const int tid  = threadIdx.x;
    const int lane = tid & 63;
    const int wave = tid >> 6;
    const int wm = wave >> 1, wn = wave & 1;
    const int l15 = lane & 15, lhi = lane >> 4;

    const int bid = blockIdx.x;
    const int nt = bid & 3;
    const int ks = (bid >> 2) & 3;
    const int mt = bid >> 4;
    const int m0g = mt * BM, n0g = nt * BN, kbase = ks * KPER;

    // A staging: 2 threads per row
    const int ar = tid >> 1;
    const int ah = tid & 1;
    const int abrow = m0g + ar;

    // B staging: j constant per thread across iters ((it*256+tid)&127 == tid&127)
    const int bj  = tid & 127;
    const int bjg = n0g + bj;
    const float bscale = PRE ? 1.0f : scale[bjg];

    char* AsB = (char*)AsF;
    char* BsB = (char*)BsF;

    f32x4 acc[4][4] = {};

    for (int step = 0; step < STEPS; ++step) {
        const int k0 = kbase + step * BK;

        // ---- stage A: zero row (64B / 80B split), then scatter tpow pieces ----
        {
            char* rb = AsB + ar * 144;
            u32x4 z = {};
            if (ah == 0) {
#pragma unroll
                for (int z4 = 0; z4 < 4; ++z4) *(u32x4*)(rb + z4 * 16) = z;
            } else {
#pragma unroll
                for (int z4 = 4; z4 < 9; ++z4) *(u32x4*)(rb + z4 * 16) = z;
            }
            // up to 3 i-blocks overlap a 64-wide chunk; ah=0 -> {0,2}, ah=1 -> {1}
            const int ifirst = k0 / 36;
#pragma unroll
            for (int ii = 0; ii < 2; ++ii) {
                const int cand = ah + ii * 2;
                const int i = ifirst + cand;
                if (cand < 3 && i * 36 < k0 + BK && i < IN_DIM) {
                    unsigned int w0, w1; int s;
                    if (PRE) {
                        uint2 r = tp[(long)abrow * IN_DIM + i];
                        w0 = r.x; w1 = r.y;
                        s = sg[(long)abrow * IN_DIM + i];
                    } else {
                        spline_rec(x[(long)abrow * IN_DIM + i], w0, w1, s);
                    }
                    const int off = i * 36 + s * 4 - k0;   // even; pieces never straddle chunk
                    if (off >= 0 && off <= 62)
                        *(unsigned int*)(rb + off * 2) = w0;
                    const int off2 = off + 2;
                    if (off2 >= 0 && off2 <= 62)
                        *(unsigned int*)(rb + off2 * 2) = w1;
                }
            }
        }

        // ---- stage B: 4 x 16B per thread, fragment-order LDS (dest = q*16, linear) ----
#pragma unroll
        for (int it = 0; it < 4; ++it) {
            const int q  = it * 256 + tid;
            const int c  = q >> 7;               // k-octet 0..7
            const int kk = k0 + c * 8;
            char* dst = BsB + q * 16;
            if (PRE) {
                u32x4 v = *(const u32x4*)((const char*)cbf + (long)bjg * (KTOT * 2) + (long)kk * 2);
                *(u32x4*)dst = v;
            } else {
                f32x4 a = *(const f32x4*)(coeff + (long)bjg * KTOT + kk);
                f32x4 b = *(const f32x4*)(coeff + (long)bjg * KTOT + kk + 4);
                u32x4 o;
                o.x = f2bf(a.x * bscale) | (f2bf(a.y * bscale) << 16);
                o.y = f2bf(a.z * bscale) | (f2bf(a.w * bscale) << 16);
                o.z = f2bf(b.x * bscale) | (f2bf(b.y * bscale) << 16);
                o.w = f2bf(b.z * bscale) | (f2bf(b.w * bscale) << 16);
                *(u32x4*)dst = o;
            }
        }

        __syncthreads();

        // ---- compute: 2 k-halves x 4x4 fragments ----
#pragma unroll
        for (int kh = 0; kh < 2; ++kh) {
            const int kk = kh * 32;
            s16x8 a[4], b[4];
#pragma unroll
            for (int mf = 0; mf < 4; ++mf)
                a[mf] = *(const s16x8*)(AsB + (wm * 64 + mf * 16 + l15) * 144 + (kk + lhi * 8) * 2);
#pragma unroll
            for (int nf = 0; nf < 4; ++nf)
                b[nf] = *(const s16x8*)(BsB + (kh * 4 + lhi) * 2048 + (wn * 64 + nf * 16 + l15) * 16);
#pragma unroll
            for (int mf = 0; mf < 4; ++mf)
#pragma unroll
                for (int nf = 0; nf < 4; ++nf)
                    acc[mf][nf] = __builtin_amdgcn_mfma_f32_16x16x32_bf16(a[mf], b[nf], acc[mf][nf], 0, 0, 0);
        }

        __syncthreads();
    }

    // ---- epilogue: split-K accumulate. C/D: col=lane&15 (n), row=(lane>>4)*4+e (m) ----
#pragma unroll
    for (int mf = 0; mf < 4; ++mf) {
        const int cmBase = m0g + wm * 64 + mf * 16 + lhi * 4;
#pragma unroll
        for (int nf = 0; nf < 4; ++nf) {
            const int cn = n0g + wn * 64 + nf * 16 + l15;
#pragma unroll
            for (int e = 0; e < 4; ++e)
                atomicAdd(out + (long)(cmBase + e) * OUT_DIM + cn, acc[mf][nf][e]);
        }
    }
}

extern "C" void kernel_launch(void* const* d_in, const int* in_sizes, int n_in,
                              void* d_out, int out_size, void* d_ws, size_t ws_size,
                              hipStream_t stream) {
    const float* x     = (const float*)d_in[0];
    const float* coeff = (const float*)d_in[1];
    const float* scale = (const float*)d_in[2];
    float* out = (float*)d_out;

    const size_t SZ_CBF = (size_t)OUT_DIM * KTOT * 2;   // 18,874,368
    const size_t SZ_TP  = (size_t)B_DIM * IN_DIM * 8;   // 16,777,216
    const size_t SZ_SG  = (size_t)B_DIM * IN_DIM;       //  2,097,152
    const size_t NEED   = SZ_CBF + SZ_TP + SZ_SG;       // ~37.75 MB

    // split-K accumulates into out: zero it every call
    hipMemsetAsync(d_out, 0, (size_t)B_DIM * OUT_DIM * sizeof(float), stream);

    if (ws_size >= NEED) {
        unsigned short* cbf = (unsigned short*)d_ws;
        uint2*          tp  = (uint2*)((char*)d_ws + SZ_CBF);
        unsigned char*  sg  = (unsigned char*)((char*)d_ws + SZ_CBF + SZ_TP);
        prep_coeff_kernel<<<4608, 256, 0, stream>>>(coeff, scale, (u32x4*)cbf);
        prep_x_kernel<<<8192, 256, 0, stream>>>(x, tp, sg);
        kan_gemm<true><<<512, 256, 0, stream>>>(x, coeff, scale, cbf, tp, sg, out);
    } else {
        kan_gemm<false><<<512, 256, 0, stream>>>(x, coeff, scale, nullptr, nullptr, nullptr, out);
    }
}

// Round 2
// 157.538 us; speedup vs baseline: 1.4079x; 1.4079x over previous
//
#include <hip/hip_runtime.h>

#define B_DIM   4096
#define IN_DIM  512
#define OUT_DIM 512
#define KTOT    (IN_DIM * 36)      // 18432
#define BM      128
#define BN      128
#define BK      64
#define KSPLIT  8
#define KPER    (KTOT / KSPLIT)    // 2304 (multiple of 64)
#define STEPS   (KPER / BK)        // 36

using f32x4 = __attribute__((ext_vector_type(4))) float;
using s16x8 = __attribute__((ext_vector_type(8))) short;
using u32x4 = __attribute__((ext_vector_type(4))) unsigned int;

// f32 -> bf16 RNE (bit pattern in low 16)
__device__ __forceinline__ unsigned int f2bf(float f) {
    unsigned int u = __float_as_uint(f);
    return (u + 0x7FFFu + ((u >> 16) & 1u)) >> 16;
}

// async global->LDS, 16B per lane (dest must be wave-uniform base + lane*16)
__device__ __forceinline__ void glds16(const void* g, void* l) {
    __builtin_amdgcn_global_load_lds(
        (const __attribute__((address_space(1))) unsigned int*)g,
        (__attribute__((address_space(3))) unsigned int*)l,
        16, 0, 0);
}

// Exact replication of np.linspace(-1,1,10) + searchsorted(knots[1:], xc, 'left') + clip.
__device__ __forceinline__ uint2 spline_rec_packed(float xv) {
    float xc = fminf(fmaxf(xv, -1.0f), 1.0f);
    double xd = (double)xc;
    int s = 0;
#pragma unroll
    for (int k = 1; k <= 8; ++k)
        s += ((-1.0 + (double)k * (2.0 / 9.0)) < xd) ? 1 : 0;
    double lo = -1.0 + (double)s * (2.0 / 9.0);
    double hi = -1.0 + (double)(s + 1) * (2.0 / 9.0);
    float t  = (float)((xd - lo) / (hi - lo));
    float t2 = t * t, t3 = t2 * t;
    uint2 r;
    r.x = f2bf(t)  | (f2bf(t2) << 16);              // {t, t2}
    r.y = f2bf(t3) | ((unsigned int)s << 16);       // {t3, seg}
    return r;
}

// Prepass 1: per (b,i) packed tpow+seg record (8B)
__global__ void prep_x_kernel(const float* __restrict__ x, uint2* __restrict__ tp) {
    int idx = blockIdx.x * 256 + threadIdx.x;
    if (idx >= B_DIM * IN_DIM) return;
    tp[idx] = spline_rec_packed(x[idx]);
}

// Prepass 2: coeff f32 -> bf16, scale[j] folded in. Layout [OUT][KTOT] bf16.
__global__ void prep_coeff_kernel(const float* __restrict__ c,
                                  const float* __restrict__ scale,
                                  u32x4* __restrict__ cbf) {
    int idx = blockIdx.x * 256 + threadIdx.x;           // one per 8 f32
    if (idx >= (OUT_DIM * KTOT) / 8) return;
    long base = (long)idx * 8;
    int  j = (int)(base / KTOT);                        // 18432 % 8 == 0: no row straddle
    float s = scale[j];
    f32x4 a = *(const f32x4*)(c + base);
    f32x4 b = *(const f32x4*)(c + base + 4);
    u32x4 o;
    o.x = f2bf(a.x * s) | (f2bf(a.y * s) << 16);
    o.y = f2bf(a.z * s) | (f2bf(a.w * s) << 16);
    o.z = f2bf(b.x * s) | (f2bf(b.y * s) << 16);
    o.w = f2bf(b.z * s) | (f2bf(b.w * s) << 16);
    cbf[idx] = o;
}

// scatter one record into the fragment-order A tile (octet-half owned by ah)
__device__ __forceinline__ void scat(char* AsB, int ar, int ah, uint2 rec, int i, int k0) {
    if (i * 36 < k0 + BK && i < IN_DIM) {
        int s   = (int)(rec.y >> 16);
        int off = i * 36 + s * 4 - k0;                  // multiple of 4
        if (off >= 0 && off <= 60) {
            int oct = off >> 3;
            if ((oct >> 2) == ah) {                     // own octet half -> race-free
                uint2 w;
                w.x = 0x3F80u | (rec.x << 16);          // {1, t}
                w.y = (rec.x >> 16) | (rec.y << 16);    // {t2, t3}
                *(uint2*)(AsB + oct * 2048 + ar * 16 + ((off >> 2) & 1) * 8) = w;
            }
        }
    }
}

__device__ __forceinline__ void load_recs(const uint2* __restrict__ tpRow, int k0,
                                          uint2& q0, uint2& q1, uint2& q2) {
    int ifirst = k0 / 36;                               // <= 510
    q0 = tpRow[ifirst];
    q1 = tpRow[ifirst + 1];                             // <= 511, always in-bounds
    q2 = tpRow[ifirst + 2 < IN_DIM ? ifirst + 2 : 0];   // guarded; skipped in scat if OOB
}

// GEMM: y[b,j] += sum_k A[b,k]*Cbf[j,k]. Fragment-order LDS for both A and B.
// Grid 1024 = 32 mt x 8 ks x 4 nt. 256 threads = 4 waves, each wave 64x64 out.
__launch_bounds__(256, 4)
__global__ void kan_gemm_fast(const unsigned short* __restrict__ cbf,
                              const uint2* __restrict__ tp,
                              float* __restrict__ out) {
    // [8 oct][128 row][16B]: entry (oct,row) holds A[row][k0+oct*8 .. +8)
    __shared__ unsigned short AsF[8 * BM * 8];          // 16 KB
    __shared__ unsigned short BsF[8 * BN * 8];          // 16 KB

    const int tid  = threadIdx.x;
    const int lane = tid & 63;
    const int wave = tid >> 6;
    const int wm = wave >> 1, wn = wave & 1;
    const int l15 = lane & 15, lhi = lane >> 4;

    const int bid = blockIdx.x;
    const int nt = bid & 3;
    const int ks = (bid >> 2) & 7;
    const int mt = bid >> 5;
    const int m0g = mt * BM, n0g = nt * BN, kbase = ks * KPER;

    const int ar = tid >> 1;         // row 0..127, 2 threads per row
    const int ah = tid & 1;          // octet half owner
    const int bjg = n0g + (tid & 127);
    const int tidHi = tid >> 7;

    char* AsB = (char*)AsF;
    char* BsB = (char*)BsF;
    const uint2* tpRow = tp + (long)(m0g + ar) * IN_DIM;
    const char*  bRow  = (const char*)cbf + (long)bjg * (KTOT * 2);

    uint2 r0, r1, r2;
    load_recs(tpRow, kbase, r0, r1, r2);

    f32x4 acc[4][4] = {};

    for (int step = 0; step < STEPS; ++step) {
        const int k0 = kbase + step * BK;

        // ---- A: zero own 4 octets (contiguous b128, bank-balanced), then scatter ----
        u32x4 z = {};
#pragma unroll
        for (int zi = 0; zi < 4; ++zi)
            *(u32x4*)(AsB + (ah * 4 + zi) * 2048 + ar * 16) = z;
        {
            const int ifirst = k0 / 36;
            scat(AsB, ar, ah, r0, ifirst,     k0);
            scat(AsB, ar, ah, r1, ifirst + 1, k0);
            scat(AsB, ar, ah, r2, ifirst + 2, k0);
        }

        // ---- B: async global->LDS, 4 x 16B per thread, fragment-order dest ----
#pragma unroll
        for (int it = 0; it < 4; ++it) {
            const int q    = it * 256 + tid;
            const int koct = it * 2 + tidHi;
            glds16(bRow + (long)(k0 + koct * 8) * 2, BsB + q * 16);
        }

        __syncthreads();   // drains vmcnt (B in LDS) + lgkm (A writes)

        // prefetch next step's A records; the drain at the NEXT barrier hides them under MFMA
        if (step + 1 < STEPS)
            load_recs(tpRow, k0 + BK, r0, r1, r2);

        // ---- compute: 2 k-halves x 4x4 fragments ----
#pragma unroll
        for (int kh = 0; kh < 2; ++kh) {
            s16x8 a[4], b[4];
#pragma unroll
            for (int mf = 0; mf < 4; ++mf)
                a[mf] = *(const s16x8*)(AsB + (kh * 4 + lhi) * 2048 + (wm * 64 + mf * 16 + l15) * 16);
#pragma unroll
            for (int nf = 0; nf < 4; ++nf)
                b[nf] = *(const s16x8*)(BsB + (kh * 4 + lhi) * 2048 + (wn * 64 + nf * 16 + l15) * 16);
#pragma unroll
            for (int mf = 0; mf < 4; ++mf)
#pragma unroll
                for (int nf = 0; nf < 4; ++nf)
                    acc[mf][nf] = __builtin_amdgcn_mfma_f32_16x16x32_bf16(a[mf], b[nf], acc[mf][nf], 0, 0, 0);
        }

        __syncthreads();
    }

    // ---- epilogue: split-K accumulate. C/D: col=lane&15 (n), row=(lane>>4)*4+e (m) ----
#pragma unroll
    for (int mf = 0; mf < 4; ++mf) {
        const int cmBase = m0g + wm * 64 + mf * 16 + lhi * 4;
#pragma unroll
        for (int nf = 0; nf < 4; ++nf) {
            const int cn = n0g + wn * 64 + nf * 16 + l15;
#pragma unroll
            for (int e = 0; e < 4; ++e)
                atomicAdd(out + (long)(cmBase + e) * OUT_DIM + cn, acc[mf][nf][e]);
        }
    }
}

// ---------------- fallback (no workspace): round-1 proven kernel, non-PRE ----------------
#define FKPER  4608
#define FSTEPS 72
__launch_bounds__(256, 2)
__global__ void kan_gemm_ref(const float* __restrict__ x,
                             const float* __restrict__ coeff,
                             const float* __restrict__ scale,
                             float* __restrict__ out) {
    __shared__ unsigned short AsF[BM * 72];
    __shared__ unsigned short BsF[8 * BN * 8];
    const int tid  = threadIdx.x;
    const int lane = tid & 63;
    const int wave = tid >> 6;
    const int wm = wave >> 1, wn = wave & 1;
    const int l15 = lane & 15, lhi = lane >> 4;
    const int bid = blockIdx.x;
    const int nt = bid & 3;
    const int ks = (bid >> 2) & 3;
    const int mt = bid >> 4;
    const int m0g = mt * BM, n0g = nt * BN, kbase = ks * FKPER;
    const int ar = tid >> 1, ah = tid & 1;
    const int abrow = m0g + ar;
    const int bjg = n0g + (tid & 127);
    const float bscale = scale[bjg];
    char* AsB = (char*)AsF;
    char* BsB = (char*)BsF;
    f32x4 acc[4][4] = {};
    for (int step = 0; step < FSTEPS; ++step) {
        const int k0 = kbase + step * BK;
        {
            char* rb = AsB + ar * 144;
            u32x4 z = {};
            if (ah == 0) {
#pragma unroll
                for (int z4 = 0; z4 < 4; ++z4) *(u32x4*)(rb + z4 * 16) = z;
            } else {
#pragma unroll
                for (int z4 = 4; z4 < 9; ++z4) *(u32x4*)(rb + z4 * 16) = z;
            }
            const int ifirst = k0 / 36;
#pragma unroll
            for (int ii = 0; ii < 2; ++ii) {
                const int cand = ah + ii * 2;
                const int i = ifirst + cand;
                if (cand < 3 && i * 36 < k0 + BK && i < IN_DIM) {
                    uint2 rec = spline_rec_packed(x[(long)abrow * IN_DIM + i]);
                    int s = (int)(rec.y >> 16);
                    const int off = i * 36 + s * 4 - k0;
                    unsigned int w0 = 0x3F80u | (rec.x << 16);
                    unsigned int w1 = (rec.x >> 16) | (rec.y << 16);
                    if (off >= 0 && off <= 62) *(unsigned int*)(rb + off * 2) = w0;
                    const int off2 = off + 2;
                    if (off2 >= 0 && off2 <= 62) *(unsigned int*)(rb + off2 * 2) = w1;
                }
            }
        }
#pragma unroll
        for (int it = 0; it < 4; ++it) {
            const int q  = it * 256 + tid;
            const int c  = q >> 7;
            const int kk = k0 + c * 8;
            f32x4 a = *(const f32x4*)(coeff + (long)bjg * KTOT + kk);
            f32x4 b = *(const f32x4*)(coeff + (long)bjg * KTOT + kk + 4);
            u32x4 o;
            o.x = f2bf(a.x * bscale) | (f2bf(a.y * bscale) << 16);
            o.y = f2bf(a.z * bscale) | (f2bf(a.w * bscale) << 16);
            o.z = f2bf(b.x * bscale) | (f2bf(b.y * bscale) << 16);
            o.w = f2bf(b.z * bscale) | (f2bf(b.w * bscale) << 16);
            *(u32x4*)(BsB + q * 16) = o;
        }
        __syncthreads();
#pragma unroll
        for (int kh = 0; kh < 2; ++kh) {
            const int kk = kh * 32;
            s16x8 a[4], b[4];
#pragma unroll
            for (int mf = 0; mf < 4; ++mf)
                a[mf] = *(const s16x8*)(AsB + (wm * 64 + mf * 16 + l15) * 144 + (kk + lhi * 8) * 2);
#pragma unroll
            for (int nf = 0; nf < 4; ++nf)
                b[nf] = *(const s16x8*)(BsB + (kh * 4 + lhi) * 2048 + (wn * 64 + nf * 16 + l15) * 16);
#pragma unroll
            for (int mf = 0; mf < 4; ++mf)
#pragma unroll
                for (int nf = 0; nf < 4; ++nf)
                    acc[mf][nf] = __builtin_amdgcn_mfma_f32_16x16x32_bf16(a[mf], b[nf], acc[mf][nf], 0, 0, 0);
        }
        __syncthreads();
    }
#pragma unroll
    for (int mf = 0; mf < 4; ++mf) {
        const int cmBase = m0g + wm * 64 + mf * 16 + lhi * 4;
#pragma unroll
        for (int nf = 0; nf < 4; ++nf) {
            const int cn = n0g + wn * 64 + nf * 16 + l15;
#pragma unroll
            for (int e = 0; e < 4; ++e)
                atomicAdd(out + (long)(cmBase + e) * OUT_DIM + cn, acc[mf][nf][e]);
        }
    }
}

extern "C" void kernel_launch(void* const* d_in, const int* in_sizes, int n_in,
                              void* d_out, int out_size, void* d_ws, size_t ws_size,
                              hipStream_t stream) {
    const float* x     = (const float*)d_in[0];
    const float* coeff = (const float*)d_in[1];
    const float* scale = (const float*)d_in[2];
    float* out = (float*)d_out;

    const size_t SZ_CBF = (size_t)OUT_DIM * KTOT * 2;   // 18,874,368
    const size_t SZ_TP  = (size_t)B_DIM * IN_DIM * 8;   // 16,777,216
    const size_t NEED   = SZ_CBF + SZ_TP;               // ~35.7 MB

    // split-K accumulates into out: zero it every call
    hipMemsetAsync(d_out, 0, (size_t)B_DIM * OUT_DIM * sizeof(float), stream);

    if (ws_size >= NEED) {
        unsigned short* cbf = (unsigned short*)d_ws;
        uint2*          tp  = (uint2*)((char*)d_ws + SZ_CBF);
        prep_coeff_kernel<<<4608, 256, 0, stream>>>(coeff, scale, (u32x4*)cbf);
        prep_x_kernel<<<8192, 256, 0, stream>>>(x, tp);
        kan_gemm_fast<<<1024, 256, 0, stream>>>(cbf, tp, out);
    } else {
        kan_gemm_ref<<<512, 256, 0, stream>>>(x, coeff, scale, out);
    }
}